// Round 3
// baseline (309.721 us; speedup 1.0000x reference)
//
#include <hip/hip_runtime.h>
#include <math.h>

#define BB 64
#define SS 1024
#define DD 32
#define HH 2
#define DHH 16
#define VV 28
#define TK 128
#define NSPLIT 4      // fixed 256-key ranges; split sp covers [sp*256, sp*256+256)
#define KCH 256

// ---------------- kernel 1: blocks 0..63: last-index; block 64: W2 = wfc@wo ----------------
__global__ void k_pre(const float* __restrict__ mask,
                      const float* __restrict__ wo, const float* __restrict__ bo,
                      const float* __restrict__ wfc, const float* __restrict__ bfc,
                      int* __restrict__ e, float* __restrict__ W2, float* __restrict__ b2) {
    if (blockIdx.x < BB) {
        int b = blockIdx.x;
        int lm = -1;
        for (int s = threadIdx.x; s < SS; s += blockDim.x)
            if (mask[b * SS + s] != 0.0f) lm = s;
        __shared__ int red[256];
        red[threadIdx.x] = lm;
        __syncthreads();
        for (int off = 128; off > 0; off >>= 1) {
            if (threadIdx.x < off) red[threadIdx.x] = max(red[threadIdx.x], red[threadIdx.x + off]);
            __syncthreads();
        }
        if (threadIdx.x == 0) {
            int last = red[0];
            int ee = last;
            if (last < SS - 1) ee = min(last + 3, SS - 1);
            e[b] = ee;   // nm[s] = (s <= e); kmax = e+1
        }
    } else {
        for (int tid = threadIdx.x; tid < VV * DD + VV; tid += blockDim.x) {
            if (tid < VV * DD) {
                int vv = tid / DD, i = tid % DD;
                float a = 0.0f;
                for (int j = 0; j < DD; j++) a += wfc[vv * DD + j] * wo[j * DD + i];
                W2[tid] = a;
            } else {
                int vv = tid - VV * DD;
                float a = bfc[vv];
                for (int j = 0; j < DD; j++) a += wfc[vv * DD + j] * bo[j];
                b2[vv] = a;
            }
        }
    }
}

// ---------------- kernel 2: h = (emb[x]+pe)*nm ; q,k,v projections ----------------
// nm[s] == mask[max(s-3,0)]  (valid because lengths <= S-4 -> extension always applies)
__global__ void k_qkv(const int* __restrict__ x, const float* __restrict__ emb,
                      const float* __restrict__ pe, const float* __restrict__ mask,
                      const float* __restrict__ wq, const float* __restrict__ bq,
                      const float* __restrict__ wk, const float* __restrict__ bk,
                      const float* __restrict__ wv, const float* __restrict__ bv,
                      float* __restrict__ q, float* __restrict__ k, float* __restrict__ v) {
    __shared__ float sWq[DD * DD], sWk[DD * DD], sWv[DD * DD];
    __shared__ float sBq[DD], sBk[DD], sBv[DD];
    for (int i = threadIdx.x; i < DD * DD; i += blockDim.x) {
        sWq[i] = wq[i]; sWk[i] = wk[i]; sWv[i] = wv[i];
    }
    if (threadIdx.x < DD) {
        sBq[threadIdx.x] = bq[threadIdx.x];
        sBk[threadIdx.x] = bk[threadIdx.x];
        sBv[threadIdx.x] = bv[threadIdx.x];
    }
    __syncthreads();

    int idx = blockIdx.x * blockDim.x + threadIdx.x;
    int b = idx / SS, s = idx % SS;
    float nm = (mask[b * SS + (s >= 3 ? s - 3 : 0)] != 0.0f) ? 1.0f : 0.0f;
    int tok = x[idx];

    float h[DD];
#pragma unroll
    for (int i = 0; i < DD; i++) h[i] = (emb[tok * DD + i] + pe[s * DD + i]) * nm;

#pragma unroll
    for (int i = 0; i < DD; i++) {
        float aq = sBq[i], ak = sBk[i], av = sBv[i];
#pragma unroll
        for (int j = 0; j < DD; j++) {
            aq += h[j] * sWq[i * DD + j];
            ak += h[j] * sWk[i * DD + j];
            av += h[j] * sWv[i * DD + j];
        }
        q[(size_t)idx * DD + i] = aq;
        k[(size_t)idx * DD + i] = ak;
        v[(size_t)idx * DD + i] = av;
    }
}

// ---------------- kernel 3: equal-work split-K flash attention ----------------
// grid (S/256, B*H, NSPLIT). Split sp covers keys [sp*KCH, sp*KCH+KCH) ∩ [0,kmax).
// Empty splits exit without writing; combine reads only ceil(kmax/KCH) splits.
__global__ void k_attn(const float* __restrict__ q, const float* __restrict__ k,
                       const float* __restrict__ v, const int* __restrict__ e,
                       float* __restrict__ pm, float* __restrict__ pl,
                       float* __restrict__ pacc) {
    int bh = blockIdx.y;
    int b = bh / HH, hh = bh % HH;
    int sp = blockIdx.z;
    int qi = blockIdx.x * blockDim.x + threadIdx.x;

    int kmax = e[b] + 1;
    int k0 = sp * KCH;
    if (k0 >= kmax) return;                  // block-uniform early exit
    int k1 = min(kmax, k0 + KCH);

    __shared__ float sk[TK][DHH];
    __shared__ float sv[TK][DHH];

    const float* qp = q + ((size_t)(b * SS + qi)) * DD + hh * DHH;
    float qv[DHH];
#pragma unroll
    for (int i = 0; i < DHH; i++) qv[i] = qp[i] * 0.25f;   // 1/sqrt(DH)

    float m = -1e30f, l = 0.0f;
    float acc[DHH];
#pragma unroll
    for (int i = 0; i < DHH; i++) acc[i] = 0.0f;

    for (int kt = k0; kt < k1; kt += TK) {
        int kn = min(TK, k1 - kt);
        __syncthreads();
        {
            int r = threadIdx.x & (TK - 1);
            if (r < kn) {
                const float* src = (threadIdx.x < TK ? k : v)
                                   + ((size_t)(b * SS + kt + r)) * DD + hh * DHH;
                float* dst = (threadIdx.x < TK ? &sk[r][0] : &sv[r][0]);
#pragma unroll
                for (int i = 0; i < DHH; i += 4)
                    *(float4*)&dst[i] = *(const float4*)&src[i];
            }
        }
        __syncthreads();

        for (int j0 = 0; j0 < kn; j0 += 8) {
            float p[8];
            // 8 independent dots (clamped rows for the tail, predicated scores)
#pragma unroll
            for (int jj = 0; jj < 8; jj++) {
                int j = j0 + jj;
                int jc = min(j, kn - 1);
                float d0 = qv[0] * sk[jc][0], d1 = qv[1] * sk[jc][1];
                float d2 = qv[2] * sk[jc][2], d3 = qv[3] * sk[jc][3];
#pragma unroll
                for (int i = 4; i < DHH; i += 4) {
                    d0 += qv[i]     * sk[jc][i];
                    d1 += qv[i + 1] * sk[jc][i + 1];
                    d2 += qv[i + 2] * sk[jc][i + 2];
                    d3 += qv[i + 3] * sk[jc][i + 3];
                }
                float sc = (d0 + d1) + (d2 + d3);
                p[jj] = (j < kn) ? sc : -1e30f;
            }
            // group max
            float g01 = fmaxf(p[0], p[1]), g23 = fmaxf(p[2], p[3]);
            float g45 = fmaxf(p[4], p[5]), g67 = fmaxf(p[6], p[7]);
            float gmax = fmaxf(fmaxf(g01, g23), fmaxf(g45, g67));
            float nmx = fmaxf(m, gmax);
            float scale = __expf(m - nmx);
            // 8 independent exps
            float psum = 0.0f;
#pragma unroll
            for (int jj = 0; jj < 8; jj++) { p[jj] = __expf(p[jj] - nmx); }
            psum = ((p[0] + p[1]) + (p[2] + p[3])) + ((p[4] + p[5]) + (p[6] + p[7]));
            // rescale once per group, then 8 independent fma streams per i
#pragma unroll
            for (int i = 0; i < DHH; i++) acc[i] *= scale;
#pragma unroll
            for (int jj = 0; jj < 8; jj++) {
                int jc = min(j0 + jj, kn - 1);
                float pj = p[jj];
#pragma unroll
                for (int i = 0; i < DHH; i++) acc[i] += pj * sv[jc][i];
            }
            l = l * scale + psum;
            m = nmx;
        }
    }
    size_t pi = ((size_t)bh * SS + qi) * NSPLIT + sp;
    pm[pi] = m;
    pl[pi] = l;
#pragma unroll
    for (int i = 0; i < DHH; i += 4)
        *(float4*)&pacc[pi * DHH + i] = *(const float4*)&acc[i];
}

// ---------------- kernel 4: combine partials + out = o @ W2^T + b2 ----------------
__global__ void k_fc(const float* __restrict__ pm, const float* __restrict__ pl,
                     const float* __restrict__ pacc, const int* __restrict__ e,
                     const float* __restrict__ W2, const float* __restrict__ b2,
                     float* __restrict__ out) {
    __shared__ float sW[VV * DD];
    __shared__ float sB[VV];
    for (int i = threadIdx.x; i < VV * DD; i += blockDim.x) sW[i] = W2[i];
    if (threadIdx.x < VV) sB[threadIdx.x] = b2[threadIdx.x];
    __syncthreads();

    int idx = blockIdx.x * blockDim.x + threadIdx.x;    // [0, B*S)
    int b = idx / SS, s = idx % SS;
    int nsp = (e[b] + 1 + KCH - 1) / KCH;               // live splits (block-uniform)

    float o_[DD];
#pragma unroll
    for (int hh = 0; hh < HH; hh++) {
        size_t base = ((size_t)(b * HH + hh) * SS + s) * NSPLIT;
        float mm[NSPLIT], ll[NSPLIT];
#pragma unroll
        for (int sp = 0; sp < NSPLIT; sp++) {
            if (sp < nsp) { mm[sp] = pm[base + sp]; ll[sp] = pl[base + sp]; }
            else          { mm[sp] = -1e30f;        ll[sp] = 0.0f; }
        }
        float M = fmaxf(fmaxf(mm[0], mm[1]), fmaxf(mm[2], mm[3]));
        float ss[NSPLIT];
        float l = 0.0f;
#pragma unroll
        for (int sp = 0; sp < NSPLIT; sp++) {
            ss[sp] = (sp < nsp) ? __expf(mm[sp] - M) : 0.0f;
            l += ll[sp] * ss[sp];
        }
        float inv = 1.0f / l;
#pragma unroll
        for (int i = 0; i < DHH; i++) {
            float a = 0.0f;
#pragma unroll
            for (int sp = 0; sp < NSPLIT; sp++) {
                if (sp < nsp) a += pacc[(base + sp) * DHH + i] * ss[sp];
            }
            o_[hh * DHH + i] = a * inv;
        }
    }

#pragma unroll
    for (int vv = 0; vv < VV; vv++) {
        float a = sB[vv];
#pragma unroll
        for (int j = 0; j < DD; j++) a += o_[j] * sW[vv * DD + j];
        out[(size_t)idx * VV + vv] = a;
    }
}

extern "C" void kernel_launch(void* const* d_in, const int* in_sizes, int n_in,
                              void* d_out, int out_size, void* d_ws, size_t ws_size,
                              hipStream_t stream) {
    const int*   x    = (const int*)d_in[0];
    const float* mask = (const float*)d_in[1];
    const float* emb  = (const float*)d_in[2];
    const float* pe   = (const float*)d_in[3];
    const float* wq   = (const float*)d_in[4];
    const float* bq   = (const float*)d_in[5];
    const float* wk   = (const float*)d_in[6];
    const float* bk   = (const float*)d_in[7];
    const float* wv   = (const float*)d_in[8];
    const float* bv   = (const float*)d_in[9];
    const float* wo   = (const float*)d_in[10];
    const float* bo   = (const float*)d_in[11];
    const float* wfc  = (const float*)d_in[12];
    const float* bfc  = (const float*)d_in[13];
    float* out = (float*)d_out;

    char* ws = (char*)d_ws;
    const size_t BSD = (size_t)BB * SS * DD * sizeof(float);        // 8 MiB
    const size_t NQ  = (size_t)BB * HH * SS;                        // 131072
    int*   e    = (int*)ws;                                         // 64 ints
    float* q    = (float*)(ws + 4096);
    float* k    = (float*)(ws + 4096 + BSD);
    float* v    = (float*)(ws + 4096 + 2 * BSD);
    float* W2   = (float*)(ws + 4096 + 3 * BSD);                    // 64 KiB region
    float* b2   = W2 + VV * DD;
    float* pm   = (float*)(ws + 4096 + 3 * BSD + 65536);            // 2 MiB
    float* pl   = pm + NQ * NSPLIT;                                 // 2 MiB
    float* pacc = pl + NQ * NSPLIT;                                 // 32 MiB

    hipLaunchKernelGGL(k_pre, dim3(BB + 1), dim3(256), 0, stream,
                       mask, wo, bo, wfc, bfc, e, W2, b2);
    hipLaunchKernelGGL(k_qkv, dim3(BB * SS / 256), dim3(256), 0, stream,
                       x, emb, pe, mask, wq, bq, wk, bk, wv, bv, q, k, v);
    hipLaunchKernelGGL(k_attn, dim3(SS / 256, BB * HH, NSPLIT), dim3(256), 0, stream,
                       q, k, v, e, pm, pl, pacc);
    hipLaunchKernelGGL(k_fc, dim3(BB * SS / 256), dim3(256), 0, stream,
                       pm, pl, pacc, e, W2, b2, out);
}

// Round 4
// 225.320 us; speedup vs baseline: 1.3746x; 1.3746x over previous
//
#include <hip/hip_runtime.h>
#include <math.h>

#define BB 64
#define SS 1024
#define DD 32
#define HH 2
#define DHH 16
#define VV 28

typedef __attribute__((ext_vector_type(8))) short bf16x8;
typedef __attribute__((ext_vector_type(4))) float f32x4;

__device__ __forceinline__ unsigned short bf_rtne(float x) {
    unsigned u = __float_as_uint(x);
    return (unsigned short)((u + 0x7FFFu + ((u >> 16) & 1u)) >> 16);
}

// ---------------- kernel 1: blocks [0,768): qkv (mat=bid%3); [768,832): e; 832: W2 ----------------
__global__ void k_pre(const int* __restrict__ x, const float* __restrict__ mask,
                      const float* __restrict__ emb, const float* __restrict__ pe,
                      const float* __restrict__ wq, const float* __restrict__ bq,
                      const float* __restrict__ wk, const float* __restrict__ bk,
                      const float* __restrict__ wv, const float* __restrict__ bv,
                      const float* __restrict__ wo, const float* __restrict__ bo,
                      const float* __restrict__ wfc, const float* __restrict__ bfc,
                      int* __restrict__ e, float* __restrict__ W2, float* __restrict__ b2,
                      float* __restrict__ q, float* __restrict__ k, float* __restrict__ v) {
    int bid = blockIdx.x;
    if (bid < 768) {
        int mat = bid % 3;
        const float* W    = mat == 0 ? wq : (mat == 1 ? wk : wv);
        const float* bias = mat == 0 ? bq : (mat == 1 ? bk : bv);
        float* outm       = mat == 0 ? q  : (mat == 1 ? k  : v);
        __shared__ float sW[DD * DD];
        __shared__ float sB[DD];
        for (int i = threadIdx.x; i < DD * DD; i += 256) sW[i] = W[i];
        if (threadIdx.x < DD) sB[threadIdx.x] = bias[threadIdx.x];
        __syncthreads();
        int idx = (bid / 3) * 256 + threadIdx.x;
        int b = idx >> 10, s = idx & 1023;
        float nm = (mask[b * SS + (s >= 3 ? s - 3 : 0)] != 0.0f) ? 1.0f : 0.0f;
        int tok = x[idx];
        float h[DD];
#pragma unroll
        for (int i = 0; i < DD; i++) h[i] = (emb[tok * DD + i] + pe[s * DD + i]) * nm;
#pragma unroll
        for (int i = 0; i < DD; i++) {
            float a = sB[i];
#pragma unroll
            for (int j = 0; j < DD; j++) a += h[j] * sW[i * DD + j];
            outm[(size_t)idx * DD + i] = a;
        }
    } else if (bid < 832) {
        int b = bid - 768;
        int lm = -1;
        for (int s = threadIdx.x; s < SS; s += 256)
            if (mask[b * SS + s] != 0.0f) lm = s;
        __shared__ int red[256];
        red[threadIdx.x] = lm;
        __syncthreads();
        for (int off = 128; off > 0; off >>= 1) {
            if (threadIdx.x < off) red[threadIdx.x] = max(red[threadIdx.x], red[threadIdx.x + off]);
            __syncthreads();
        }
        if (threadIdx.x == 0) {
            int last = red[0];
            int ee = last;
            if (last < SS - 1) ee = min(last + 3, SS - 1);
            e[b] = ee;   // kmax = e+1
        }
    } else {
        for (int tid = threadIdx.x; tid < VV * DD + VV; tid += 256) {
            if (tid < VV * DD) {
                int vv = tid / DD, i = tid % DD;
                float a = 0.0f;
                for (int j = 0; j < DD; j++) a += wfc[vv * DD + j] * wo[j * DD + i];
                W2[tid] = a;
            } else {
                int vv = tid - VV * DD;
                float a = bfc[vv];
                for (int j = 0; j < DD; j++) a += wfc[vv * DD + j] * bo[j];
                b2[vv] = a;
            }
        }
    }
}

// ---------------- kernel 2: MFMA flash attention + fused W2 FC ----------------
// grid 2048: b = id&63 (swizzle for balance), qt = id>>6; block = 32 queries x 2 heads.
// wave w: queries (w>>1)*16.., head w&1.
__global__ void k_attn(const float* __restrict__ q, const float* __restrict__ k,
                       const float* __restrict__ v, const int* __restrict__ e,
                       const float* __restrict__ W2, const float* __restrict__ b2,
                       float* __restrict__ out) {
    // LDS map (bytes):
    //   [0,4608)      Kb: 32 keys x 144 (per key: h0[kh16|kl16] h1[kh16|kl16] pad16), bf16
    //   [4608,9728)   Vb: 64 rows x 80  (row = h*32 + half*16 + dh; 32 keys bf16 + pad)
    //   [0,4608)      Ob (alias after K-loop): 32 q x 36 floats
    //   [9728,14848)  Pb: 4 waves x (16 q x 80B)
    //   [14848,18880) sW: 28 x 36 floats ; [18880,18992) sb
    __shared__ __align__(16) char smem[19008];
    char*  Kb = smem;
    char*  Vb = smem + 4608;
    float* Ob = (float*)smem;
    char*  Pb = smem + 9728;
    float* sW = (float*)(smem + 14848);
    float* sb = (float*)(smem + 18880);

    int tid = threadIdx.x;
    int b = blockIdx.x & 63, qt = blockIdx.x >> 6;
    int s0 = qt * 32;
    int wave = tid >> 6, lane = tid & 63, quad = lane >> 4, c = lane & 15;
    int h = wave & 1;
    int qbase = s0 + (wave >> 1) * 16;
    int kmax = e[b] + 1;

    for (int i = tid; i < VV * DD; i += 256) sW[(i >> 5) * 36 + (i & 31)] = W2[i];
    if (tid < VV) sb[tid] = b2[tid];

    // ---- Q A-frag: A = [qh(16 dims) | ql(16 dims)], k-dim = quad*8+j ----
    bf16x8 aQ;
    {
        const float* qp = q + ((size_t)(b * SS + qbase + c)) * DD + h * DHH + (quad & 1) * 8;
        float4 qa = *(const float4*)qp;
        float4 qb = *(const float4*)(qp + 4);
        float t[8] = {qa.x, qa.y, qa.z, qa.w, qb.x, qb.y, qb.z, qb.w};
#pragma unroll
        for (int j = 0; j < 8; j++) {
            float xv = t[j] * 0.25f;                       // fold 1/sqrt(DH)
            unsigned u = __float_as_uint(xv);
            if (quad < 2) {
                aQ[j] = (short)(u >> 16);                  // hi (trunc split)
            } else {
                float hi = __uint_as_float(u & 0xFFFF0000u);
                aQ[j] = (short)(__float_as_uint(xv - hi) >> 16);   // lo
            }
        }
    }

    f32x4 accO = {0.0f, 0.0f, 0.0f, 0.0f};
    const f32x4 zero4 = {0.0f, 0.0f, 0.0f, 0.0f};
    float m_[4], l_[4];
#pragma unroll
    for (int r = 0; r < 4; r++) { m_[r] = -3e38f; l_[r] = 0.0f; }

    int skey = tid >> 3, d0 = (tid & 7) * 4;
    int shh = d0 >> 4, sdh = d0 & 15;
    char* Pw = Pb + wave * 1280;

    for (int kt = 0; kt < kmax; kt += 32) {
        __syncthreads();
        // ---- stage K (hi/lo, [key][dims]) and V (hi/lo, [dh][key] transposed) ----
        {
            size_t row = (size_t)(b * SS + kt + skey) * DD + d0;   // kt+skey <= 1023 always
            float4 kf = *(const float4*)(k + row);
            float4 vf = *(const float4*)(v + row);
            unsigned u0 = __float_as_uint(kf.x), u1 = __float_as_uint(kf.y);
            unsigned u2 = __float_as_uint(kf.z), u3 = __float_as_uint(kf.w);
            uint2 khp, klp;
            khp.x = (u0 >> 16) | (u1 & 0xFFFF0000u);
            khp.y = (u2 >> 16) | (u3 & 0xFFFF0000u);
            float r0 = kf.x - __uint_as_float(u0 & 0xFFFF0000u);
            float r1 = kf.y - __uint_as_float(u1 & 0xFFFF0000u);
            float r2 = kf.z - __uint_as_float(u2 & 0xFFFF0000u);
            float r3 = kf.w - __uint_as_float(u3 & 0xFFFF0000u);
            klp.x = (__float_as_uint(r0) >> 16) | (__float_as_uint(r1) & 0xFFFF0000u);
            klp.y = (__float_as_uint(r2) >> 16) | (__float_as_uint(r3) & 0xFFFF0000u);
            char* kr = Kb + skey * 144 + shh * 64 + sdh * 2;
            *(uint2*)kr = khp;
            *(uint2*)(kr + 32) = klp;
            float ve[4] = {vf.x, vf.y, vf.z, vf.w};
#pragma unroll
            for (int j = 0; j < 4; j++) {
                unsigned uv = __float_as_uint(ve[j]);
                *(short*)(Vb + (shh * 32 + sdh + j) * 80 + skey * 2) = (short)(uv >> 16);
                float rv = ve[j] - __uint_as_float(uv & 0xFFFF0000u);
                *(short*)(Vb + (shh * 32 + 16 + sdh + j) * 80 + skey * 2) =
                    (short)(__float_as_uint(rv) >> 16);
            }
        }
        __syncthreads();

        // ---- QK^T: 2 key-tiles, 2 MFMAs each (B1=[kh;kh], B2=[kl;kl]) ----
        f32x4 st[2];
#pragma unroll
        for (int tile = 0; tile < 2; tile++) {
            const char* kb = Kb + (tile * 16 + c) * 144 + h * 64 + (quad & 1) * 16;
            bf16x8 bkh = *(const bf16x8*)kb;
            bf16x8 bkl = *(const bf16x8*)(kb + 32);
            f32x4 s = __builtin_amdgcn_mfma_f32_16x16x32_bf16(aQ, bkl, zero4, 0, 0, 0);
            s = __builtin_amdgcn_mfma_f32_16x16x32_bf16(aQ, bkh, s, 0, 0, 0);
            if (kt + tile * 16 + c >= kmax) { s[0] = -3e38f; s[1] = -3e38f; s[2] = -3e38f; s[3] = -3e38f; }
            st[tile] = s;
        }
        // ---- online softmax (rows r: q = quad*4+r) ----
        float tm[4];
#pragma unroll
        for (int r = 0; r < 4; r++) tm[r] = fmaxf(st[0][r], st[1][r]);
#pragma unroll
        for (int d = 1; d < 16; d <<= 1) {
#pragma unroll
            for (int r = 0; r < 4; r++) tm[r] = fmaxf(tm[r], __shfl_xor(tm[r], d, 16));
        }
        float p0[4], p1[4];
#pragma unroll
        for (int r = 0; r < 4; r++) {
            float mn = fmaxf(m_[r], tm[r]);
            float sc = __expf(m_[r] - mn);
            m_[r] = mn;
            p0[r] = __expf(st[0][r] - mn);
            p1[r] = __expf(st[1][r] - mn);
            l_[r] = l_[r] * sc + p0[r] + p1[r];
            accO[r] *= sc;
        }
        // ---- P transpose via LDS (C-layout -> A-layout), bf16 RTNE ----
#pragma unroll
        for (int r = 0; r < 4; r++) {
            *(short*)(Pw + (quad * 4 + r) * 80 + c * 2)        = (short)bf_rtne(p0[r]);
            *(short*)(Pw + (quad * 4 + r) * 80 + (16 + c) * 2) = (short)bf_rtne(p1[r]);
        }
        bf16x8 aP = *(const bf16x8*)(Pw + c * 80 + quad * 16);
        // ---- PV: O += P*(Vh + Vl) ----
        const char* vb = Vb + (h * 32 + c) * 80 + quad * 16;
        bf16x8 bvh = *(const bf16x8*)vb;
        bf16x8 bvl = *(const bf16x8*)(vb + 16 * 80);
        accO = __builtin_amdgcn_mfma_f32_16x16x32_bf16(aP, bvl, accO, 0, 0, 0);
        accO = __builtin_amdgcn_mfma_f32_16x16x32_bf16(aP, bvh, accO, 0, 0, 0);
    }

    // ---- finalize: l row-sum, normalize ----
#pragma unroll
    for (int d = 1; d < 16; d <<= 1) {
#pragma unroll
        for (int r = 0; r < 4; r++) l_[r] += __shfl_xor(l_[r], d, 16);
    }
    float o_[4];
#pragma unroll
    for (int r = 0; r < 4; r++) o_[r] = accO[r] / l_[r];

    __syncthreads();   // everyone done with Kb/Vb; safe to alias as Ob
#pragma unroll
    for (int r = 0; r < 4; r++)
        Ob[((wave >> 1) * 16 + quad * 4 + r) * 36 + h * DHH + c] = o_[r];
    __syncthreads();

    // ---- fused FC: out = O @ W2^T + b2 ----
    int qloc = tid >> 3, j = tid & 7;
    const float* orow = Ob + qloc * 36;
    float ov[32];
#pragma unroll
    for (int i = 0; i < 32; i += 4) {
        float4 t = *(const float4*)(orow + i);
        ov[i] = t.x; ov[i + 1] = t.y; ov[i + 2] = t.z; ov[i + 3] = t.w;
    }
    size_t obase = (size_t)(b * SS + s0 + qloc) * VV;
#pragma unroll
    for (int jj = 0; jj < 4; jj++) {
        int vv = j + jj * 8;
        if (vv < VV) {
            float a = sb[vv];
#pragma unroll
            for (int d = 0; d < DD; d++) a += ov[d] * sW[vv * 36 + d];
            out[obase + vv] = a;
        }
    }
}

extern "C" void kernel_launch(void* const* d_in, const int* in_sizes, int n_in,
                              void* d_out, int out_size, void* d_ws, size_t ws_size,
                              hipStream_t stream) {
    const int*   x    = (const int*)d_in[0];
    const float* mask = (const float*)d_in[1];
    const float* emb  = (const float*)d_in[2];
    const float* pe   = (const float*)d_in[3];
    const float* wq   = (const float*)d_in[4];
    const float* bq   = (const float*)d_in[5];
    const float* wk   = (const float*)d_in[6];
    const float* bk   = (const float*)d_in[7];
    const float* wv   = (const float*)d_in[8];
    const float* bv   = (const float*)d_in[9];
    const float* wo   = (const float*)d_in[10];
    const float* bo   = (const float*)d_in[11];
    const float* wfc  = (const float*)d_in[12];
    const float* bfc  = (const float*)d_in[13];
    float* out = (float*)d_out;

    char* ws = (char*)d_ws;
    const size_t BSD = (size_t)BB * SS * DD;          // elements per matrix
    int*   e  = (int*)ws;                             // 256 B region
    float* W2 = (float*)(ws + 256);                   // 3584 B
    float* b2 = (float*)(ws + 4096);                  // 112 B
    float* q  = (float*)(ws + 8192);
    float* k  = q + BSD;
    float* v  = k + BSD;

    hipLaunchKernelGGL(k_pre, dim3(833), dim3(256), 0, stream,
                       x, mask, emb, pe, wq, bq, wk, bk, wv, bv, wo, bo, wfc, bfc,
                       e, W2, b2, q, k, v);
    hipLaunchKernelGGL(k_attn, dim3(BB * (SS / 32)), dim3(256), 0, stream,
                       q, k, v, e, W2, b2, out);
}